// Round 1
// baseline (590.850 us; speedup 1.0000x reference)
//
#include <hip/hip_runtime.h>

#define NB 16
#define VV 5000
#define NFD 352
#define KD 120

// ---------------------------------------------------------------------------
// Generic TN SGEMM 64x64 tile: C[m0:+64, n0:+64] += sum_v A[v,m]*B[v,n]
// A: [V, M] row-major, B: [V, N] row-major, C: [M, N] row-major.
// Block = 256 threads (16x16), each thread computes a 4x4 micro-tile.
// ---------------------------------------------------------------------------
__device__ __forceinline__ void gemm_tn_64x64(
    const float* __restrict__ A, const float* __restrict__ B, float* __restrict__ C,
    int V, int M, int N, int m0, int n0)
{
    __shared__ float As[16][64];
    __shared__ float Bs[16][64];

    const int tid = threadIdx.x;
    const int tx = tid & 15;          // micro-tile col group
    const int ty = tid >> 4;          // micro-tile row group
    const int sr = tid >> 4;          // staging row (v within tile)
    const int sc = (tid & 15) << 2;   // staging col*4

    float acc[4][4] = {{0.f,0.f,0.f,0.f},{0.f,0.f,0.f,0.f},
                       {0.f,0.f,0.f,0.f},{0.f,0.f,0.f,0.f}};

    for (int v0 = 0; v0 < V; v0 += 16) {
        const int v = v0 + sr;
        float4 av; av.x = av.y = av.z = av.w = 0.f;
        float4 bv; bv.x = bv.y = bv.z = bv.w = 0.f;
        if (v < V) {
            const float* Ar = A + (size_t)v * M;
            const int ca = m0 + sc;
            if (ca + 3 < M) {
                av = *(const float4*)(Ar + ca);
            } else {
                if (ca + 0 < M) av.x = Ar[ca + 0];
                if (ca + 1 < M) av.y = Ar[ca + 1];
                if (ca + 2 < M) av.z = Ar[ca + 2];
                if (ca + 3 < M) av.w = Ar[ca + 3];
            }
            const float* Br = B + (size_t)v * N;
            const int cb = n0 + sc;
            if (cb + 3 < N) {
                bv = *(const float4*)(Br + cb);
            } else {
                if (cb + 0 < N) bv.x = Br[cb + 0];
                if (cb + 1 < N) bv.y = Br[cb + 1];
                if (cb + 2 < N) bv.z = Br[cb + 2];
                if (cb + 3 < N) bv.w = Br[cb + 3];
            }
        }
        __syncthreads();  // protect previous iteration's reads
        *(float4*)&As[sr][sc] = av;
        *(float4*)&Bs[sr][sc] = bv;
        __syncthreads();

        #pragma unroll
        for (int kk = 0; kk < 16; ++kk) {
            const float4 a4 = *(const float4*)&As[kk][ty << 2];
            const float4 b4 = *(const float4*)&Bs[kk][tx << 2];
            const float a[4]  = {a4.x, a4.y, a4.z, a4.w};
            const float bb[4] = {b4.x, b4.y, b4.z, b4.w};
            #pragma unroll
            for (int i = 0; i < 4; ++i)
                #pragma unroll
                for (int j = 0; j < 4; ++j)
                    acc[i][j] = fmaf(a[i], bb[j], acc[i][j]);
        }
    }

    #pragma unroll
    for (int i = 0; i < 4; ++i) {
        const int m = m0 + (ty << 2) + i;
        if (m < M) {
            #pragma unroll
            for (int j = 0; j < 4; ++j) {
                const int n = n0 + (tx << 2) + j;
                if (n < N) C[(size_t)m * N + n] = acc[i][j];
            }
        }
    }
}

// ---------------------------------------------------------------------------
// Projection: F_hat[b,f,k] = sum_v feat[b,v,f]*evecs[b,v,k]  -> [B, 352, 120]
// grid: x = 6 mtiles * 2 ntiles = 12, y = which (0=F,1=G), z = batch
// ---------------------------------------------------------------------------
__global__ __launch_bounds__(256) void proj_kernel(
    const float* __restrict__ feat_x, const float* __restrict__ feat_y,
    const float* __restrict__ evecs_x, const float* __restrict__ evecs_y,
    float* __restrict__ fhat, float* __restrict__ ghat)
{
    const int b = blockIdx.z;
    const int which = blockIdx.y;
    const int xm = blockIdx.x % 6;
    const int xn = blockIdx.x / 6;

    const float* A  = (which == 0 ? feat_x  : feat_y)  + (size_t)b * VV * NFD;
    const float* Bp = (which == 0 ? evecs_x : evecs_y) + (size_t)b * VV * KD;
    float*       C  = (which == 0 ? fhat    : ghat)    + (size_t)b * NFD * KD;

    gemm_tn_64x64(A, Bp, C, VV, NFD, KD, xm * 64, xn * 64);
}

// ---------------------------------------------------------------------------
// Gram: FtF/GtG/FtG [b,k,l] = sum_f A[b,f,k]*B[b,f,l]  (GtF = FtG^T, skipped)
// grid: x = 2x2 tiles, y = which (0=FtF,1=GtG,2=FtG), z = batch
// ---------------------------------------------------------------------------
__global__ __launch_bounds__(256) void gram_kernel(
    const float* __restrict__ fhat, const float* __restrict__ ghat,
    float* __restrict__ ftf, float* __restrict__ gtg, float* __restrict__ ftg)
{
    const int b = blockIdx.z;
    const int which = blockIdx.y;
    const int m0 = (blockIdx.x & 1) * 64;
    const int n0 = (blockIdx.x >> 1) * 64;

    const float* F = fhat + (size_t)b * NFD * KD;
    const float* G = ghat + (size_t)b * NFD * KD;
    const float* A  = (which == 1) ? G : F;
    const float* Bp = (which == 0) ? F : G;
    float* C = ((which == 0) ? ftf : (which == 1) ? gtg : ftg) + (size_t)b * KD * KD;

    gemm_tn_64x64(A, Bp, C, NFD, KD, KD, m0, n0);
}

// ---------------------------------------------------------------------------
// Solve: pair 0: X = inv(FtF)*FtG, out C1 = X^T
//        pair 1: X = inv(GtG)*GtF (GtF read as FtG^T), out C2 = X^T
// Gauss-Jordan, no pivoting (A is SPD, cond ~15). Augmented [A|B] 120x240 held
// in registers: 16x16 threads, each owns 8 rows x 15 cols (static indexing
// only — runtime-indexed reg arrays spill to scratch). LDS broadcasts the
// pivot row/col; next step's pivot row/col is published during the update
// (double-buffered, one barrier per step).
// ---------------------------------------------------------------------------
__global__ __launch_bounds__(256) void solve_kernel(
    const float* __restrict__ ftf, const float* __restrict__ gtg,
    const float* __restrict__ ftg, float* __restrict__ out)
{
    const int pair = blockIdx.x;
    const int b = blockIdx.y;
    const int tid = threadIdx.x;
    const int tx = tid & 15;
    const int ty = tid >> 4;

    const float* Ag = ((pair == 0) ? ftf : gtg) + (size_t)b * KD * KD;
    const float* Bg = ftg + (size_t)b * KD * KD;

    float r[8][15];

    __shared__ float prow[2][240];
    __shared__ float pcol[2][128];   // 128: pad so dead rows (120..127) stay in-bounds

    // ---- load [A | B]; rows >= 120 are dead (zeros, never escape) ----
    #pragma unroll
    for (int ri = 0; ri < 8; ++ri) {
        const int i = ri * 16 + ty;
        #pragma unroll
        for (int ci = 0; ci < 15; ++ci) {
            const int c = ci * 16 + tx;
            float v = 0.f;
            if (i < KD) {
                if (c < KD) {
                    v = Ag[i * KD + c];
                } else {
                    const int l = c - KD;
                    v = (pair == 0) ? Bg[i * KD + l] : Bg[l * KD + i];
                }
            }
            r[ri][ci] = v;
        }
    }

    // ---- publish pivot row 0 / col 0 into buffer 0 ----
    if (ty == 0) {
        #pragma unroll
        for (int ci = 0; ci < 15; ++ci) prow[0][ci * 16 + tx] = r[0][ci];
    }
    if (tx == 0) {
        #pragma unroll
        for (int ri = 0; ri < 8; ++ri) pcol[0][ri * 16 + ty] = r[ri][0];
    }
    __syncthreads();

    for (int j = 0; j < KD; ++j) {
        const int p  = j & 1;
        const int jr = j >> 4;
        const int jy = j & 15;

        const float piv  = prow[p][j];
        const float pinv = 1.0f / piv;

        float prs[15], fs[8];
        #pragma unroll
        for (int ci = 0; ci < 15; ++ci) prs[ci] = prow[p][ci * 16 + tx] * pinv;
        #pragma unroll
        for (int ri = 0; ri < 8; ++ri) fs[ri] = pcol[p][ri * 16 + ty];

        #pragma unroll
        for (int ri = 0; ri < 8; ++ri) {
            if (ri == jr) {  // uniform branch: this row group contains pivot row
                const bool pr = (ty == jy);
                #pragma unroll
                for (int ci = 0; ci < 15; ++ci) {
                    const float f = fmaf(-fs[ri], prs[ci], r[ri][ci]);
                    r[ri][ci] = pr ? prs[ci] : f;   // pivot row -> scaled row
                }
            } else {
                #pragma unroll
                for (int ci = 0; ci < 15; ++ci)
                    r[ri][ci] = fmaf(-fs[ri], prs[ci], r[ri][ci]);
            }
        }

        // ---- publish NEXT pivot row/col (j+1) into buffer p^1 ----
        const int j2  = j + 1;
        const int jr2 = j2 >> 4;
        const int jy2 = j2 & 15;
        #pragma unroll
        for (int ri = 0; ri < 8; ++ri) {
            if (ri == jr2 && ty == jy2) {
                #pragma unroll
                for (int ci = 0; ci < 15; ++ci) prow[p ^ 1][ci * 16 + tx] = r[ri][ci];
            }
        }
        #pragma unroll
        for (int ci = 0; ci < 15; ++ci) {
            if (ci == jr2 && tx == jy2) {   // col j2: tx == j2&15, ci == j2>>4
                #pragma unroll
                for (int ri = 0; ri < 8; ++ri) pcol[p ^ 1][ri * 16 + ty] = r[ri][ci];
            }
        }
        __syncthreads();
    }

    // ---- write out X^T: out[pair][b][l][k] = X[k][l] ----
    float* op = out + (size_t)pair * NB * KD * KD + (size_t)b * KD * KD;
    #pragma unroll
    for (int ri = 0; ri < 8; ++ri) {
        const int i = ri * 16 + ty;
        if (i < KD) {
            #pragma unroll
            for (int ci = 0; ci < 15; ++ci) {
                const int c = ci * 16 + tx;
                if (c >= KD) op[(size_t)(c - KD) * KD + i] = r[ri][ci];
            }
        }
    }
}

// ---------------------------------------------------------------------------
extern "C" void kernel_launch(void* const* d_in, const int* in_sizes, int n_in,
                              void* d_out, int out_size, void* d_ws, size_t ws_size,
                              hipStream_t stream)
{
    const float* feat_x  = (const float*)d_in[0];
    const float* feat_y  = (const float*)d_in[1];
    const float* evecs_x = (const float*)d_in[2];
    const float* evecs_y = (const float*)d_in[3];
    float* out = (float*)d_out;

    // workspace layout (floats): fhat(675840) ghat(675840) ftf gtg ftg (230400 ea)
    // total = 2,042,880 floats = 8.2 MB
    float* ws   = (float*)d_ws;
    float* fhat = ws;
    float* ghat = fhat + (size_t)NB * NFD * KD;
    float* ftf  = ghat + (size_t)NB * NFD * KD;
    float* gtg  = ftf  + (size_t)NB * KD * KD;
    float* ftg  = gtg  + (size_t)NB * KD * KD;

    proj_kernel <<<dim3(12, 2, NB), 256, 0, stream>>>(feat_x, feat_y, evecs_x, evecs_y, fhat, ghat);
    gram_kernel <<<dim3(4, 3, NB), 256, 0, stream>>>(fhat, ghat, ftf, gtg, ftg);
    solve_kernel<<<dim3(2, NB), 256, 0, stream>>>(ftf, gtg, ftg, out);
}

// Round 2
// 280.687 us; speedup vs baseline: 2.1050x; 2.1050x over previous
//
#include <hip/hip_runtime.h>
#include <hip/hip_bf16.h>

#define NB 16
#define VV 5000
#define NFD 352
#define KD 120

typedef __attribute__((ext_vector_type(8))) short short8;
typedef __attribute__((ext_vector_type(4))) float float4v;

// ---------------------------------------------------------------------------
// helpers
// ---------------------------------------------------------------------------
__device__ __forceinline__ void load_lds16(const float* g, float* l) {
    __builtin_amdgcn_global_load_lds(
        (const __attribute__((address_space(1))) unsigned int*)g,
        (__attribute__((address_space(3))) unsigned int*)l, 16, 0, 0);
}

__device__ __forceinline__ short bfbits(const __hip_bfloat16 h) {
    return (short)__builtin_bit_cast(unsigned short, h);
}

// read 8 fp32 at stride STRIDE from LDS, emit bf16 hi/lo split fragments
template <int STRIDE>
__device__ __forceinline__ void cvt_frag(const float* p, short8& hi, short8& lo) {
    #pragma unroll
    for (int j = 0; j < 8; ++j) {
        const float a = p[j * STRIDE];
        const __hip_bfloat16 h = __float2bfloat16(a);      // RNE
        const float hf = __bfloat162float(h);
        const __hip_bfloat16 l = __float2bfloat16(a - hf); // residual
        hi[j] = bfbits(h);
        lo[j] = bfbits(l);
    }
}

// ---------------------------------------------------------------------------
// proj: F_hat[b,f,k] = sum_v feat[b,v,f] * evecs[b,v,k]
// MFMA 16x16x32 bf16 split-hi/lo (3 products). Tile: BM=96 x BN=128, BK=64.
// grid.x = mt(4) | ch(4)<<2 ; grid.y = which ; grid.z = batch. 512 blocks.
// Partial sums per V-chunk -> partials slabs [352][128] f32.
// LDS fp32 staged via global_load_lds w/ XOR m-group swizzle (s = ((k>>3)&3)<<1)
// so per-lane fragment gathers hit <=2-way bank conflicts.
// ---------------------------------------------------------------------------
__global__ __launch_bounds__(256, 2) void proj_mfma(
    const float* __restrict__ fx, const float* __restrict__ fy,
    const float* __restrict__ ex, const float* __restrict__ ey,
    float* __restrict__ partials, const float* __restrict__ zeropad)
{
    const int t  = threadIdx.x;
    const int mt = blockIdx.x & 3;
    const int ch = blockIdx.x >> 2;
    const int wh = blockIdx.y;
    const int b  = blockIdx.z;

    const float* Ab = (wh ? fy : fx) + (size_t)b * VV * NFD;
    const float* Bb = (wh ? ey : ex) + (size_t)b * VV * KD;
    const int m0 = mt * 96;

    __shared__ float ldsA[64 * 96];    // 24 KB
    __shared__ float ldsB[64 * 128];   // 32 KB

    // ---- staging address precompute (A: 6 x 16B/thread, B: 8 x 16B/thread) ----
    int akk[6]; const float* asrc0[6]; bool aok[6];
    #pragma unroll
    for (int i = 0; i < 6; ++i) {
        const int e  = i * 1024 + t * 4;      // float slot in A plane
        const int k  = e / 96;                // k row
        const int c4 = (e - k * 96) >> 2;     // physical 4-float group
        const int s  = ((k >> 3) & 3) << 1;
        const int mg = c4 ^ s;                // logical m group
        const int col = m0 + (mg << 2);
        akk[i] = k;
        aok[i] = (col < NFD);
        asrc0[i] = Ab + col;
    }
    int bkk[8]; const float* bsrc0[8]; bool bok[8];
    #pragma unroll
    for (int i = 0; i < 8; ++i) {
        const int e  = i * 1024 + t * 4;
        const int k  = e >> 7;
        const int c4 = (e >> 2) & 31;
        const int s  = ((k >> 3) & 3) << 1;
        const int ng = c4 ^ s;
        const int col = ng << 2;
        bkk[i] = k;
        bok[i] = (col < KD);
        bsrc0[i] = Bb + col;
    }

    // ---- wave / lane geometry: 4 waves as 2(m) x 2(n); wave tile 48 x 64 ----
    const int wid = t >> 6;
    const int lane = t & 63;
    const int wm = wid >> 1, wn = wid & 1;
    const int row16 = lane & 15;
    const int g = lane >> 4;
    const int sl = (g & 3) << 1;   // swizzle for this lane's k-group (indep of ksub)

    int aidx[3];
    #pragma unroll
    for (int mf = 0; mf < 3; ++mf) {
        const int m = wm * 48 + mf * 16 + row16;
        aidx[mf] = (g * 8) * 96 + ((((m >> 2) ^ sl)) << 2) + (m & 3);
    }
    int bidx[4];
    #pragma unroll
    for (int nf = 0; nf < 4; ++nf) {
        const int n = wn * 64 + nf * 16 + row16;
        bidx[nf] = (g * 8) * 128 + ((((n >> 2) ^ sl)) << 2) + (n & 3);
    }

    float4v acc[3][4];
    #pragma unroll
    for (int mf = 0; mf < 3; ++mf)
        #pragma unroll
        for (int nf = 0; nf < 4; ++nf)
            acc[mf][nf] = float4v{0.f, 0.f, 0.f, 0.f};

    const int step0  = ch * 20;
    const int nsteps = (ch < 3) ? 20 : 19;   // 79 k-steps of 64 cover V=5000

    for (int st = 0; st < nsteps; ++st) {
        const int v0 = (step0 + st) * 64;

        #pragma unroll
        for (int i = 0; i < 6; ++i) {
            const int v = v0 + akk[i];
            const float* src = (aok[i] && v < VV) ? (asrc0[i] + (size_t)v * NFD) : zeropad;
            load_lds16(src, &ldsA[i * 1024 + t * 4]);
        }
        #pragma unroll
        for (int i = 0; i < 8; ++i) {
            const int v = v0 + bkk[i];
            const float* src = (bok[i] && v < VV) ? (bsrc0[i] + (size_t)v * KD) : zeropad;
            load_lds16(src, &ldsB[i * 1024 + t * 4]);
        }
        __syncthreads();   // drains vmcnt (global_load_lds) per compiler semantics

        #pragma unroll
        for (int ks = 0; ks < 2; ++ks) {
            short8 ah[3], al[3], bh[4], bl[4];
            #pragma unroll
            for (int mf = 0; mf < 3; ++mf)
                cvt_frag<96>(&ldsA[ks * 32 * 96 + aidx[mf]], ah[mf], al[mf]);
            #pragma unroll
            for (int nf = 0; nf < 4; ++nf)
                cvt_frag<128>(&ldsB[ks * 32 * 128 + bidx[nf]], bh[nf], bl[nf]);

            #pragma unroll
            for (int mf = 0; mf < 3; ++mf)
                #pragma unroll
                for (int nf = 0; nf < 4; ++nf) {
                    acc[mf][nf] = __builtin_amdgcn_mfma_f32_16x16x32_bf16(ah[mf], bh[nf], acc[mf][nf], 0, 0, 0);
                    acc[mf][nf] = __builtin_amdgcn_mfma_f32_16x16x32_bf16(ah[mf], bl[nf], acc[mf][nf], 0, 0, 0);
                    acc[mf][nf] = __builtin_amdgcn_mfma_f32_16x16x32_bf16(al[mf], bh[nf], acc[mf][nf], 0, 0, 0);
                }
        }
        __syncthreads();
    }

    // ---- store partial C tile: slab[(mt*96 + ...)*128 + n] ----
    float* slab = partials + (size_t)((ch * 2 + wh) * NB + b) * (352 * 128);
    #pragma unroll
    for (int mf = 0; mf < 3; ++mf) {
        const int mrow = mt * 96 + wm * 48 + mf * 16 + g * 4;
        #pragma unroll
        for (int nf = 0; nf < 4; ++nf) {
            const int n = wn * 64 + nf * 16 + row16;
            #pragma unroll
            for (int r = 0; r < 4; ++r) {
                const int m = mrow + r;
                if (m < NFD) slab[(size_t)m * 128 + n] = acc[mf][nf][r];
            }
        }
    }
}

// ---------------------------------------------------------------------------
// reduce: fhat/ghat[b][f][k] = sum_ch partials[slab(ch,wh,b)][f*128 + k]
// grid: x = 165 (165*256 == 352*120), y = wh*16 + b
// ---------------------------------------------------------------------------
__global__ __launch_bounds__(256) void reduce_k(
    const float* __restrict__ partials, float* __restrict__ fhat, float* __restrict__ ghat)
{
    const int id = blockIdx.x * 256 + threadIdx.x;
    if (id >= NFD * KD) return;
    const int wb = blockIdx.y;
    const int wh = wb >> 4;
    const int b  = wb & 15;
    const int f = id / KD;
    const int k = id - f * KD;

    const size_t slabsz = 352 * 128;
    const float* p = partials + (size_t)(wh * NB + b) * slabsz + (size_t)f * 128 + k;
    const size_t chstride = (size_t)2 * NB * slabsz;

    float s = 0.f;
    #pragma unroll
    for (int c = 0; c < 4; ++c) s += p[c * chstride];

    float* dst = (wh ? ghat : fhat) + (size_t)b * NFD * KD + id;
    *dst = s;
}

// ---------------------------------------------------------------------------
// Generic TN SGEMM 64x64 tile (unchanged from round 1) — used by gram.
// ---------------------------------------------------------------------------
__device__ __forceinline__ void gemm_tn_64x64(
    const float* __restrict__ A, const float* __restrict__ B, float* __restrict__ C,
    int V, int M, int N, int m0, int n0)
{
    __shared__ float As[16][64];
    __shared__ float Bs[16][64];

    const int tid = threadIdx.x;
    const int tx = tid & 15;
    const int ty = tid >> 4;
    const int sr = tid >> 4;
    const int sc = (tid & 15) << 2;

    float acc[4][4] = {{0.f,0.f,0.f,0.f},{0.f,0.f,0.f,0.f},
                       {0.f,0.f,0.f,0.f},{0.f,0.f,0.f,0.f}};

    for (int v0 = 0; v0 < V; v0 += 16) {
        const int v = v0 + sr;
        float4 av; av.x = av.y = av.z = av.w = 0.f;
        float4 bv; bv.x = bv.y = bv.z = bv.w = 0.f;
        if (v < V) {
            const float* Ar = A + (size_t)v * M;
            const int ca = m0 + sc;
            if (ca + 3 < M) {
                av = *(const float4*)(Ar + ca);
            } else {
                if (ca + 0 < M) av.x = Ar[ca + 0];
                if (ca + 1 < M) av.y = Ar[ca + 1];
                if (ca + 2 < M) av.z = Ar[ca + 2];
                if (ca + 3 < M) av.w = Ar[ca + 3];
            }
            const float* Br = B + (size_t)v * N;
            const int cb = n0 + sc;
            if (cb + 3 < N) {
                bv = *(const float4*)(Br + cb);
            } else {
                if (cb + 0 < N) bv.x = Br[cb + 0];
                if (cb + 1 < N) bv.y = Br[cb + 1];
                if (cb + 2 < N) bv.z = Br[cb + 2];
                if (cb + 3 < N) bv.w = Br[cb + 3];
            }
        }
        __syncthreads();
        *(float4*)&As[sr][sc] = av;
        *(float4*)&Bs[sr][sc] = bv;
        __syncthreads();

        #pragma unroll
        for (int kk = 0; kk < 16; ++kk) {
            const float4 a4 = *(const float4*)&As[kk][ty << 2];
            const float4 b4 = *(const float4*)&Bs[kk][tx << 2];
            const float a[4]  = {a4.x, a4.y, a4.z, a4.w};
            const float bb[4] = {b4.x, b4.y, b4.z, b4.w};
            #pragma unroll
            for (int i = 0; i < 4; ++i)
                #pragma unroll
                for (int j = 0; j < 4; ++j)
                    acc[i][j] = fmaf(a[i], bb[j], acc[i][j]);
        }
    }

    #pragma unroll
    for (int i = 0; i < 4; ++i) {
        const int m = m0 + (ty << 2) + i;
        if (m < M) {
            #pragma unroll
            for (int j = 0; j < 4; ++j) {
                const int n = n0 + (tx << 2) + j;
                if (n < N) C[(size_t)m * N + n] = acc[i][j];
            }
        }
    }
}

__global__ __launch_bounds__(256) void gram_kernel(
    const float* __restrict__ fhat, const float* __restrict__ ghat,
    float* __restrict__ ftf, float* __restrict__ gtg, float* __restrict__ ftg)
{
    const int b = blockIdx.z;
    const int which = blockIdx.y;
    const int m0 = (blockIdx.x & 1) * 64;
    const int n0 = (blockIdx.x >> 1) * 64;

    const float* F = fhat + (size_t)b * NFD * KD;
    const float* G = ghat + (size_t)b * NFD * KD;
    const float* A  = (which == 1) ? G : F;
    const float* Bp = (which == 0) ? F : G;
    float* C = ((which == 0) ? ftf : (which == 1) ? gtg : ftg) + (size_t)b * KD * KD;

    gemm_tn_64x64(A, Bp, C, NFD, KD, KD, m0, n0);
}

// ---------------------------------------------------------------------------
// solve (unchanged from round 1): Gauss-Jordan on [A|B], out = X^T
// ---------------------------------------------------------------------------
__global__ __launch_bounds__(256) void solve_kernel(
    const float* __restrict__ ftf, const float* __restrict__ gtg,
    const float* __restrict__ ftg, float* __restrict__ out)
{
    const int pair = blockIdx.x;
    const int b = blockIdx.y;
    const int tid = threadIdx.x;
    const int tx = tid & 15;
    const int ty = tid >> 4;

    const float* Ag = ((pair == 0) ? ftf : gtg) + (size_t)b * KD * KD;
    const float* Bg = ftg + (size_t)b * KD * KD;

    float r[8][15];

    __shared__ float prow[2][240];
    __shared__ float pcol[2][128];

    #pragma unroll
    for (int ri = 0; ri < 8; ++ri) {
        const int i = ri * 16 + ty;
        #pragma unroll
        for (int ci = 0; ci < 15; ++ci) {
            const int c = ci * 16 + tx;
            float v = 0.f;
            if (i < KD) {
                if (c < KD) {
                    v = Ag[i * KD + c];
                } else {
                    const int l = c - KD;
                    v = (pair == 0) ? Bg[i * KD + l] : Bg[l * KD + i];
                }
            }
            r[ri][ci] = v;
        }
    }

    if (ty == 0) {
        #pragma unroll
        for (int ci = 0; ci < 15; ++ci) prow[0][ci * 16 + tx] = r[0][ci];
    }
    if (tx == 0) {
        #pragma unroll
        for (int ri = 0; ri < 8; ++ri) pcol[0][ri * 16 + ty] = r[ri][0];
    }
    __syncthreads();

    for (int j = 0; j < KD; ++j) {
        const int p  = j & 1;
        const int jr = j >> 4;
        const int jy = j & 15;

        const float piv  = prow[p][j];
        const float pinv = 1.0f / piv;

        float prs[15], fs[8];
        #pragma unroll
        for (int ci = 0; ci < 15; ++ci) prs[ci] = prow[p][ci * 16 + tx] * pinv;
        #pragma unroll
        for (int ri = 0; ri < 8; ++ri) fs[ri] = pcol[p][ri * 16 + ty];

        #pragma unroll
        for (int ri = 0; ri < 8; ++ri) {
            if (ri == jr) {
                const bool pr = (ty == jy);
                #pragma unroll
                for (int ci = 0; ci < 15; ++ci) {
                    const float f = fmaf(-fs[ri], prs[ci], r[ri][ci]);
                    r[ri][ci] = pr ? prs[ci] : f;
                }
            } else {
                #pragma unroll
                for (int ci = 0; ci < 15; ++ci)
                    r[ri][ci] = fmaf(-fs[ri], prs[ci], r[ri][ci]);
            }
        }

        const int j2  = j + 1;
        const int jr2 = j2 >> 4;
        const int jy2 = j2 & 15;
        #pragma unroll
        for (int ri = 0; ri < 8; ++ri) {
            if (ri == jr2 && ty == jy2) {
                #pragma unroll
                for (int ci = 0; ci < 15; ++ci) prow[p ^ 1][ci * 16 + tx] = r[ri][ci];
            }
        }
        #pragma unroll
        for (int ci = 0; ci < 15; ++ci) {
            if (ci == jr2 && tx == jy2) {
                #pragma unroll
                for (int ri = 0; ri < 8; ++ri) pcol[p ^ 1][ri * 16 + ty] = r[ri][ci];
            }
        }
        __syncthreads();
    }

    float* op = out + (size_t)pair * NB * KD * KD + (size_t)b * KD * KD;
    #pragma unroll
    for (int ri = 0; ri < 8; ++ri) {
        const int i = ri * 16 + ty;
        if (i < KD) {
            #pragma unroll
            for (int ci = 0; ci < 15; ++ci) {
                const int c = ci * 16 + tx;
                if (c >= KD) op[(size_t)(c - KD) * KD + i] = r[ri][ci];
            }
        }
    }
}

// ---------------------------------------------------------------------------
extern "C" void kernel_launch(void* const* d_in, const int* in_sizes, int n_in,
                              void* d_out, int out_size, void* d_ws, size_t ws_size,
                              hipStream_t stream)
{
    const float* feat_x  = (const float*)d_in[0];
    const float* feat_y  = (const float*)d_in[1];
    const float* evecs_x = (const float*)d_in[2];
    const float* evecs_y = (const float*)d_in[3];
    float* out = (float*)d_out;

    // ws layout (floats):
    //   zeropad   64
    //   partials  4ch*2wh*16b slabs of 352*128 = 5,767,168
    //   fhat/ghat 675,840 each; ftf/gtg/ftg 230,400 each   (total ~31.3 MB)
    float* ws       = (float*)d_ws;
    float* zeropad  = ws;
    float* partials = ws + 64;
    float* fhat     = partials + (size_t)4 * 2 * NB * 352 * 128;
    float* ghat     = fhat + (size_t)NB * NFD * KD;
    float* ftf      = ghat + (size_t)NB * NFD * KD;
    float* gtg      = ftf  + (size_t)NB * KD * KD;
    float* ftg      = gtg  + (size_t)NB * KD * KD;

    hipMemsetAsync(zeropad, 0, 256, stream);

    proj_mfma <<<dim3(16, 2, NB), 256, 0, stream>>>(feat_x, feat_y, evecs_x, evecs_y, partials, zeropad);
    reduce_k  <<<dim3(165, 32), 256, 0, stream>>>(partials, fhat, ghat);
    gram_kernel<<<dim3(4, 3, NB), 256, 0, stream>>>(fhat, ghat, ftf, gtg, ftg);
    solve_kernel<<<dim3(2, NB), 256, 0, stream>>>(ftf, gtg, ftg, out);
}

// Round 3
// 259.946 us; speedup vs baseline: 2.2730x; 1.0798x over previous
//
#include <hip/hip_runtime.h>
#include <hip/hip_bf16.h>

#define NB 16
#define VV 5000
#define NFD 352
#define KD 120

typedef __attribute__((ext_vector_type(8))) short short8;
typedef __attribute__((ext_vector_type(4))) float float4v;

// ---------------------------------------------------------------------------
// helpers
// ---------------------------------------------------------------------------
__device__ __forceinline__ void load_lds16(const float* g, float* l) {
    __builtin_amdgcn_global_load_lds(
        (const __attribute__((address_space(1))) unsigned int*)g,
        (__attribute__((address_space(3))) unsigned int*)l, 16, 0, 0);
}

__device__ __forceinline__ short bfbits(const __hip_bfloat16 h) {
    return (short)__builtin_bit_cast(unsigned short, h);
}

// read 8 fp32 at stride STRIDE from LDS, emit bf16 hi/lo split fragments
template <int STRIDE>
__device__ __forceinline__ void cvt_frag(const float* p, short8& hi, short8& lo) {
    #pragma unroll
    for (int j = 0; j < 8; ++j) {
        const float a = p[j * STRIDE];
        const __hip_bfloat16 h = __float2bfloat16(a);      // RNE
        const float hf = __bfloat162float(h);
        const __hip_bfloat16 l = __float2bfloat16(a - hf); // residual
        hi[j] = bfbits(h);
        lo[j] = bfbits(l);
    }
}

// ---------------------------------------------------------------------------
// proj: F_hat[b,f,k] = sum_v feat[b,v,f] * evecs[b,v,k]
// MFMA 16x16x32 bf16 split-hi/lo (3 products). Tile: BM=96 x BN=128, BK=64.
// grid.x = mt(4) | ch(4)<<2 ; grid.y = which ; grid.z = batch. 512 blocks.
// ---------------------------------------------------------------------------
__global__ __launch_bounds__(256, 2) void proj_mfma(
    const float* __restrict__ fx, const float* __restrict__ fy,
    const float* __restrict__ ex, const float* __restrict__ ey,
    float* __restrict__ partials, const float* __restrict__ zeropad)
{
    const int t  = threadIdx.x;
    const int mt = blockIdx.x & 3;
    const int ch = blockIdx.x >> 2;
    const int wh = blockIdx.y;
    const int b  = blockIdx.z;

    const float* Ab = (wh ? fy : fx) + (size_t)b * VV * NFD;
    const float* Bb = (wh ? ey : ex) + (size_t)b * VV * KD;
    const int m0 = mt * 96;

    __shared__ float ldsA[64 * 96];    // 24 KB
    __shared__ float ldsB[64 * 128];   // 32 KB

    // ---- staging address precompute (A: 6 x 16B/thread, B: 8 x 16B/thread) ----
    int akk[6]; const float* asrc0[6]; bool aok[6];
    #pragma unroll
    for (int i = 0; i < 6; ++i) {
        const int e  = i * 1024 + t * 4;      // float slot in A plane
        const int k  = e / 96;                // k row
        const int c4 = (e - k * 96) >> 2;     // physical 4-float group
        const int s  = ((k >> 3) & 3) << 1;
        const int mg = c4 ^ s;                // logical m group
        const int col = m0 + (mg << 2);
        akk[i] = k;
        aok[i] = (col < NFD);
        asrc0[i] = Ab + col;
    }
    int bkk[8]; const float* bsrc0[8]; bool bok[8];
    #pragma unroll
    for (int i = 0; i < 8; ++i) {
        const int e  = i * 1024 + t * 4;
        const int k  = e >> 7;
        const int c4 = (e >> 2) & 31;
        const int s  = ((k >> 3) & 3) << 1;
        const int ng = c4 ^ s;
        const int col = ng << 2;
        bkk[i] = k;
        bok[i] = (col < KD);
        bsrc0[i] = Bb + col;
    }

    // ---- wave / lane geometry: 4 waves as 2(m) x 2(n); wave tile 48 x 64 ----
    const int wid = t >> 6;
    const int lane = t & 63;
    const int wm = wid >> 1, wn = wid & 1;
    const int row16 = lane & 15;
    const int g = lane >> 4;
    const int sl = (g & 3) << 1;

    int aidx[3];
    #pragma unroll
    for (int mf = 0; mf < 3; ++mf) {
        const int m = wm * 48 + mf * 16 + row16;
        aidx[mf] = (g * 8) * 96 + ((((m >> 2) ^ sl)) << 2) + (m & 3);
    }
    int bidx[4];
    #pragma unroll
    for (int nf = 0; nf < 4; ++nf) {
        const int n = wn * 64 + nf * 16 + row16;
        bidx[nf] = (g * 8) * 128 + ((((n >> 2) ^ sl)) << 2) + (n & 3);
    }

    float4v acc[3][4];
    #pragma unroll
    for (int mf = 0; mf < 3; ++mf)
        #pragma unroll
        for (int nf = 0; nf < 4; ++nf)
            acc[mf][nf] = float4v{0.f, 0.f, 0.f, 0.f};

    const int step0  = ch * 20;
    const int nsteps = (ch < 3) ? 20 : 19;   // 79 k-steps of 64 cover V=5000

    for (int st = 0; st < nsteps; ++st) {
        const int v0 = (step0 + st) * 64;

        #pragma unroll
        for (int i = 0; i < 6; ++i) {
            const int v = v0 + akk[i];
            const float* src = (aok[i] && v < VV) ? (asrc0[i] + (size_t)v * NFD) : zeropad;
            load_lds16(src, &ldsA[i * 1024 + t * 4]);
        }
        #pragma unroll
        for (int i = 0; i < 8; ++i) {
            const int v = v0 + bkk[i];
            const float* src = (bok[i] && v < VV) ? (bsrc0[i] + (size_t)v * KD) : zeropad;
            load_lds16(src, &ldsB[i * 1024 + t * 4]);
        }
        __syncthreads();

        #pragma unroll
        for (int ks = 0; ks < 2; ++ks) {
            short8 ah[3], al[3], bh[4], bl[4];
            #pragma unroll
            for (int mf = 0; mf < 3; ++mf)
                cvt_frag<96>(&ldsA[ks * 32 * 96 + aidx[mf]], ah[mf], al[mf]);
            #pragma unroll
            for (int nf = 0; nf < 4; ++nf)
                cvt_frag<128>(&ldsB[ks * 32 * 128 + bidx[nf]], bh[nf], bl[nf]);

            #pragma unroll
            for (int mf = 0; mf < 3; ++mf)
                #pragma unroll
                for (int nf = 0; nf < 4; ++nf) {
                    acc[mf][nf] = __builtin_amdgcn_mfma_f32_16x16x32_bf16(ah[mf], bh[nf], acc[mf][nf], 0, 0, 0);
                    acc[mf][nf] = __builtin_amdgcn_mfma_f32_16x16x32_bf16(ah[mf], bl[nf], acc[mf][nf], 0, 0, 0);
                    acc[mf][nf] = __builtin_amdgcn_mfma_f32_16x16x32_bf16(al[mf], bh[nf], acc[mf][nf], 0, 0, 0);
                }
        }
        __syncthreads();
    }

    float* slab = partials + (size_t)((ch * 2 + wh) * NB + b) * (352 * 128);
    #pragma unroll
    for (int mf = 0; mf < 3; ++mf) {
        const int mrow = mt * 96 + wm * 48 + mf * 16 + g * 4;
        #pragma unroll
        for (int nf = 0; nf < 4; ++nf) {
            const int n = wn * 64 + nf * 16 + row16;
            #pragma unroll
            for (int r = 0; r < 4; ++r) {
                const int m = mrow + r;
                if (m < NFD) slab[(size_t)m * 128 + n] = acc[mf][nf][r];
            }
        }
    }
}

// ---------------------------------------------------------------------------
// reduce: fhat/ghat[b][f][k] = sum_ch partials[slab(ch,wh,b)][f*128 + k]
// ---------------------------------------------------------------------------
__global__ __launch_bounds__(256) void reduce_k(
    const float* __restrict__ partials, float* __restrict__ fhat, float* __restrict__ ghat)
{
    const int id = blockIdx.x * 256 + threadIdx.x;
    if (id >= NFD * KD) return;
    const int wb = blockIdx.y;
    const int wh = wb >> 4;
    const int b  = wb & 15;
    const int f = id / KD;
    const int k = id - f * KD;

    const size_t slabsz = 352 * 128;
    const float* p = partials + (size_t)(wh * NB + b) * slabsz + (size_t)f * 128 + k;
    const size_t chstride = (size_t)2 * NB * slabsz;

    float s = 0.f;
    #pragma unroll
    for (int c = 0; c < 4; ++c) s += p[c * chstride];

    float* dst = (wh ? ghat : fhat) + (size_t)b * NFD * KD + id;
    *dst = s;
}

// ---------------------------------------------------------------------------
// Generic TN SGEMM 64x64 tile — used by gram.
// ---------------------------------------------------------------------------
__device__ __forceinline__ void gemm_tn_64x64(
    const float* __restrict__ A, const float* __restrict__ B, float* __restrict__ C,
    int V, int M, int N, int m0, int n0)
{
    __shared__ float As[16][64];
    __shared__ float Bs[16][64];

    const int tid = threadIdx.x;
    const int tx = tid & 15;
    const int ty = tid >> 4;
    const int sr = tid >> 4;
    const int sc = (tid & 15) << 2;

    float acc[4][4] = {{0.f,0.f,0.f,0.f},{0.f,0.f,0.f,0.f},
                       {0.f,0.f,0.f,0.f},{0.f,0.f,0.f,0.f}};

    for (int v0 = 0; v0 < V; v0 += 16) {
        const int v = v0 + sr;
        float4 av; av.x = av.y = av.z = av.w = 0.f;
        float4 bv; bv.x = bv.y = bv.z = bv.w = 0.f;
        if (v < V) {
            const float* Ar = A + (size_t)v * M;
            const int ca = m0 + sc;
            if (ca + 3 < M) {
                av = *(const float4*)(Ar + ca);
            } else {
                if (ca + 0 < M) av.x = Ar[ca + 0];
                if (ca + 1 < M) av.y = Ar[ca + 1];
                if (ca + 2 < M) av.z = Ar[ca + 2];
                if (ca + 3 < M) av.w = Ar[ca + 3];
            }
            const float* Br = B + (size_t)v * N;
            const int cb = n0 + sc;
            if (cb + 3 < N) {
                bv = *(const float4*)(Br + cb);
            } else {
                if (cb + 0 < N) bv.x = Br[cb + 0];
                if (cb + 1 < N) bv.y = Br[cb + 1];
                if (cb + 2 < N) bv.z = Br[cb + 2];
                if (cb + 3 < N) bv.w = Br[cb + 3];
            }
        }
        __syncthreads();
        *(float4*)&As[sr][sc] = av;
        *(float4*)&Bs[sr][sc] = bv;
        __syncthreads();

        #pragma unroll
        for (int kk = 0; kk < 16; ++kk) {
            const float4 a4 = *(const float4*)&As[kk][ty << 2];
            const float4 b4 = *(const float4*)&Bs[kk][tx << 2];
            const float a[4]  = {a4.x, a4.y, a4.z, a4.w};
            const float bb[4] = {b4.x, b4.y, b4.z, b4.w};
            #pragma unroll
            for (int i = 0; i < 4; ++i)
                #pragma unroll
                for (int j = 0; j < 4; ++j)
                    acc[i][j] = fmaf(a[i], bb[j], acc[i][j]);
        }
    }

    #pragma unroll
    for (int i = 0; i < 4; ++i) {
        const int m = m0 + (ty << 2) + i;
        if (m < M) {
            #pragma unroll
            for (int j = 0; j < 4; ++j) {
                const int n = n0 + (tx << 2) + j;
                if (n < N) C[(size_t)m * N + n] = acc[i][j];
            }
        }
    }
}

__global__ __launch_bounds__(256) void gram_kernel(
    const float* __restrict__ fhat, const float* __restrict__ ghat,
    float* __restrict__ ftf, float* __restrict__ gtg, float* __restrict__ ftg)
{
    const int b = blockIdx.z;
    const int which = blockIdx.y;
    const int m0 = (blockIdx.x & 1) * 64;
    const int n0 = (blockIdx.x >> 1) * 64;

    const float* F = fhat + (size_t)b * NFD * KD;
    const float* G = ghat + (size_t)b * NFD * KD;
    const float* A  = (which == 1) ? G : F;
    const float* Bp = (which == 0) ? F : G;
    float* C = ((which == 0) ? ftf : (which == 1) ? gtg : ftg) + (size_t)b * KD * KD;

    gemm_tn_64x64(A, Bp, C, NFD, KD, KD, m0, n0);
}

// ---------------------------------------------------------------------------
// solve v2: Gauss-Jordan on [A|B] 120x240, 512 threads (32 row-groups x 16
// col-groups), each thread owns r[4][15] = 60 VGPRs (register-resident — the
// v1 256-thread/120-VGPR layout spilled to scratch: VGPR_Count=76, 160 us).
// __launch_bounds__(512,1) gives the allocator the full budget.
// pair 0: X = inv(FtF)*FtG, out C1 = X^T;  pair 1: X = inv(GtG)*FtG^T, C2 = X^T
// ---------------------------------------------------------------------------
__global__ __launch_bounds__(512, 1) void solve_kernel(
    const float* __restrict__ ftf, const float* __restrict__ gtg,
    const float* __restrict__ ftg, float* __restrict__ out)
{
    const int pair = blockIdx.x;
    const int b = blockIdx.y;
    const int tid = threadIdx.x;
    const int tx = tid & 15;    // col group 0..15, col c = ci*16+tx
    const int ty = tid >> 4;    // row group 0..31, row i = ri*32+ty

    const float* Ag = ((pair == 0) ? ftf : gtg) + (size_t)b * KD * KD;
    const float* Bg = ftg + (size_t)b * KD * KD;

    float r[4][15];

    __shared__ float prow[2][240];
    __shared__ float pcol[2][128];   // rows 0..127 (120..127 dead zeros)

    // ---- load [A | B] ----
    #pragma unroll
    for (int ri = 0; ri < 4; ++ri) {
        const int i = ri * 32 + ty;
        #pragma unroll
        for (int ci = 0; ci < 15; ++ci) {
            const int c = ci * 16 + tx;
            float v = 0.f;
            if (i < KD) {
                if (c < KD) {
                    v = Ag[i * KD + c];
                } else {
                    const int l = c - KD;
                    v = (pair == 0) ? Bg[i * KD + l] : Bg[l * KD + i];
                }
            }
            r[ri][ci] = v;
        }
    }

    // ---- publish pivot row 0 / col 0 into buffer 0 ----
    if (ty == 0) {
        #pragma unroll
        for (int ci = 0; ci < 15; ++ci) prow[0][ci * 16 + tx] = r[0][ci];
    }
    if (tx == 0) {
        #pragma unroll
        for (int ri = 0; ri < 4; ++ri) pcol[0][ri * 32 + ty] = r[ri][0];
    }
    __syncthreads();

    for (int j = 0; j < KD; ++j) {
        const int p  = j & 1;
        const int jr = j >> 5;   // pivot row's ri
        const int jy = j & 31;   // pivot row's ty

        const float pinv = 1.0f / prow[p][j];

        float prs[15], fs[4];
        #pragma unroll
        for (int ci = 0; ci < 15; ++ci) prs[ci] = prow[p][ci * 16 + tx] * pinv;
        #pragma unroll
        for (int ri = 0; ri < 4; ++ri) fs[ri] = pcol[p][ri * 32 + ty];

        #pragma unroll
        for (int ri = 0; ri < 4; ++ri) {
            if (ri == jr) {   // uniform across wave rows? ty varies -> predicated
                const bool pr = (ty == jy);
                #pragma unroll
                for (int ci = 0; ci < 15; ++ci) {
                    const float f = fmaf(-fs[ri], prs[ci], r[ri][ci]);
                    r[ri][ci] = pr ? prs[ci] : f;   // pivot row -> scaled row
                }
            } else {
                #pragma unroll
                for (int ci = 0; ci < 15; ++ci)
                    r[ri][ci] = fmaf(-fs[ri], prs[ci], r[ri][ci]);
            }
        }

        // ---- publish NEXT pivot row/col (j+1) into buffer p^1 ----
        const int j2  = j + 1;
        const int jr2 = j2 >> 5;
        const int jy2 = j2 & 31;
        const int cg2 = j2 >> 4;    // pivot col's ci
        const int cx2 = j2 & 15;    // pivot col's tx
        #pragma unroll
        for (int ri = 0; ri < 4; ++ri) {
            if (ri == jr2 && ty == jy2) {
                #pragma unroll
                for (int ci = 0; ci < 15; ++ci) prow[p ^ 1][ci * 16 + tx] = r[ri][ci];
            }
        }
        #pragma unroll
        for (int ci = 0; ci < 15; ++ci) {
            if (ci == cg2 && tx == cx2) {
                #pragma unroll
                for (int ri = 0; ri < 4; ++ri) pcol[p ^ 1][ri * 32 + ty] = r[ri][ci];
            }
        }
        __syncthreads();
    }

    // ---- write out X^T: out[pair][b][l][k] = X[k][l] ----
    float* op = out + (size_t)pair * NB * KD * KD + (size_t)b * KD * KD;
    #pragma unroll
    for (int ri = 0; ri < 4; ++ri) {
        const int i = ri * 32 + ty;
        if (i < KD) {
            #pragma unroll
            for (int ci = 0; ci < 15; ++ci) {
                const int c = ci * 16 + tx;
                if (c >= KD) op[(size_t)(c - KD) * KD + i] = r[ri][ci];
            }
        }
    }
}

// ---------------------------------------------------------------------------
extern "C" void kernel_launch(void* const* d_in, const int* in_sizes, int n_in,
                              void* d_out, int out_size, void* d_ws, size_t ws_size,
                              hipStream_t stream)
{
    const float* feat_x  = (const float*)d_in[0];
    const float* feat_y  = (const float*)d_in[1];
    const float* evecs_x = (const float*)d_in[2];
    const float* evecs_y = (const float*)d_in[3];
    float* out = (float*)d_out;

    float* ws       = (float*)d_ws;
    float* zeropad  = ws;
    float* partials = ws + 64;
    float* fhat     = partials + (size_t)4 * 2 * NB * 352 * 128;
    float* ghat     = fhat + (size_t)NB * NFD * KD;
    float* ftf      = ghat + (size_t)NB * NFD * KD;
    float* gtg      = ftf  + (size_t)NB * KD * KD;
    float* ftg      = gtg  + (size_t)NB * KD * KD;

    hipMemsetAsync(zeropad, 0, 256, stream);

    proj_mfma <<<dim3(16, 2, NB), 256, 0, stream>>>(feat_x, feat_y, evecs_x, evecs_y, partials, zeropad);
    reduce_k  <<<dim3(165, 32), 256, 0, stream>>>(partials, fhat, ghat);
    gram_kernel<<<dim3(4, 3, NB), 256, 0, stream>>>(fhat, ghat, ftf, gtg, ftg);
    solve_kernel<<<dim3(2, NB), 512, 0, stream>>>(ftf, gtg, ftg, out);
}

// Round 5
// 250.019 us; speedup vs baseline: 2.3632x; 1.0397x over previous
//
#include <hip/hip_runtime.h>
#include <hip/hip_bf16.h>

#define NB 16
#define VV 5000
#define NFD 352
#define KD 120

typedef __attribute__((ext_vector_type(8))) short short8;
typedef __attribute__((ext_vector_type(4))) float float4v;

// ---------------------------------------------------------------------------
// helpers
// ---------------------------------------------------------------------------
__device__ __forceinline__ void load_lds16(const float* g, float* l) {
    __builtin_amdgcn_global_load_lds(
        (const __attribute__((address_space(1))) unsigned int*)g,
        (__attribute__((address_space(3))) unsigned int*)l, 16, 0, 0);
}

__device__ __forceinline__ short bfbits(const __hip_bfloat16 h) {
    return (short)__builtin_bit_cast(unsigned short, h);
}

// read 8 fp32 at stride STRIDE from LDS, emit bf16 hi/lo split fragments
template <int STRIDE>
__device__ __forceinline__ void cvt_frag(const float* p, short8& hi, short8& lo) {
    #pragma unroll
    for (int j = 0; j < 8; ++j) {
        const float a = p[j * STRIDE];
        const __hip_bfloat16 h = __float2bfloat16(a);      // RNE
        const float hf = __bfloat162float(h);
        const __hip_bfloat16 l = __float2bfloat16(a - hf); // residual
        hi[j] = bfbits(h);
        lo[j] = bfbits(l);
    }
}

// ---------------------------------------------------------------------------
// proj: F_hat[b,f,k] = sum_v feat[b,v,f] * evecs[b,v,k]
// MFMA 16x16x32 bf16 split-hi/lo (3 products). Tile: BM=96 x BN=128, BK=64.
// (unchanged from the round-3 passing version)
// ---------------------------------------------------------------------------
__global__ __launch_bounds__(256, 2) void proj_mfma(
    const float* __restrict__ fx, const float* __restrict__ fy,
    const float* __restrict__ ex, const float* __restrict__ ey,
    float* __restrict__ partials, const float* __restrict__ zeropad)
{
    const int t  = threadIdx.x;
    const int mt = blockIdx.x & 3;
    const int ch = blockIdx.x >> 2;
    const int wh = blockIdx.y;
    const int b  = blockIdx.z;

    const float* Ab = (wh ? fy : fx) + (size_t)b * VV * NFD;
    const float* Bb = (wh ? ey : ex) + (size_t)b * VV * KD;
    const int m0 = mt * 96;

    __shared__ float ldsA[64 * 96];    // 24 KB
    __shared__ float ldsB[64 * 128];   // 32 KB

    int akk[6]; const float* asrc0[6]; bool aok[6];
    #pragma unroll
    for (int i = 0; i < 6; ++i) {
        const int e  = i * 1024 + t * 4;
        const int k  = e / 96;
        const int c4 = (e - k * 96) >> 2;
        const int s  = ((k >> 3) & 3) << 1;
        const int mg = c4 ^ s;
        const int col = m0 + (mg << 2);
        akk[i] = k;
        aok[i] = (col < NFD);
        asrc0[i] = Ab + col;
    }
    int bkk[8]; const float* bsrc0[8]; bool bok[8];
    #pragma unroll
    for (int i = 0; i < 8; ++i) {
        const int e  = i * 1024 + t * 4;
        const int k  = e >> 7;
        const int c4 = (e >> 2) & 31;
        const int s  = ((k >> 3) & 3) << 1;
        const int ng = c4 ^ s;
        const int col = ng << 2;
        bkk[i] = k;
        bok[i] = (col < KD);
        bsrc0[i] = Bb + col;
    }

    const int wid = t >> 6;
    const int lane = t & 63;
    const int wm = wid >> 1, wn = wid & 1;
    const int row16 = lane & 15;
    const int g = lane >> 4;
    const int sl = (g & 3) << 1;

    int aidx[3];
    #pragma unroll
    for (int mf = 0; mf < 3; ++mf) {
        const int m = wm * 48 + mf * 16 + row16;
        aidx[mf] = (g * 8) * 96 + ((((m >> 2) ^ sl)) << 2) + (m & 3);
    }
    int bidx[4];
    #pragma unroll
    for (int nf = 0; nf < 4; ++nf) {
        const int n = wn * 64 + nf * 16 + row16;
        bidx[nf] = (g * 8) * 128 + ((((n >> 2) ^ sl)) << 2) + (n & 3);
    }

    float4v acc[3][4];
    #pragma unroll
    for (int mf = 0; mf < 3; ++mf)
        #pragma unroll
        for (int nf = 0; nf < 4; ++nf)
            acc[mf][nf] = float4v{0.f, 0.f, 0.f, 0.f};

    const int step0  = ch * 20;
    const int nsteps = (ch < 3) ? 20 : 19;

    for (int st = 0; st < nsteps; ++st) {
        const int v0 = (step0 + st) * 64;

        #pragma unroll
        for (int i = 0; i < 6; ++i) {
            const int v = v0 + akk[i];
            const float* src = (aok[i] && v < VV) ? (asrc0[i] + (size_t)v * NFD) : zeropad;
            load_lds16(src, &ldsA[i * 1024 + t * 4]);
        }
        #pragma unroll
        for (int i = 0; i < 8; ++i) {
            const int v = v0 + bkk[i];
            const float* src = (bok[i] && v < VV) ? (bsrc0[i] + (size_t)v * KD) : zeropad;
            load_lds16(src, &ldsB[i * 1024 + t * 4]);
        }
        __syncthreads();

        #pragma unroll
        for (int ks = 0; ks < 2; ++ks) {
            short8 ah[3], al[3], bh[4], bl[4];
            #pragma unroll
            for (int mf = 0; mf < 3; ++mf)
                cvt_frag<96>(&ldsA[ks * 32 * 96 + aidx[mf]], ah[mf], al[mf]);
            #pragma unroll
            for (int nf = 0; nf < 4; ++nf)
                cvt_frag<128>(&ldsB[ks * 32 * 128 + bidx[nf]], bh[nf], bl[nf]);

            #pragma unroll
            for (int mf = 0; mf < 3; ++mf)
                #pragma unroll
                for (int nf = 0; nf < 4; ++nf) {
                    acc[mf][nf] = __builtin_amdgcn_mfma_f32_16x16x32_bf16(ah[mf], bh[nf], acc[mf][nf], 0, 0, 0);
                    acc[mf][nf] = __builtin_amdgcn_mfma_f32_16x16x32_bf16(ah[mf], bl[nf], acc[mf][nf], 0, 0, 0);
                    acc[mf][nf] = __builtin_amdgcn_mfma_f32_16x16x32_bf16(al[mf], bh[nf], acc[mf][nf], 0, 0, 0);
                }
        }
        __syncthreads();
    }

    float* slab = partials + (size_t)((ch * 2 + wh) * NB + b) * (352 * 128);
    #pragma unroll
    for (int mf = 0; mf < 3; ++mf) {
        const int mrow = mt * 96 + wm * 48 + mf * 16 + g * 4;
        #pragma unroll
        for (int nf = 0; nf < 4; ++nf) {
            const int n = wn * 64 + nf * 16 + row16;
            #pragma unroll
            for (int r = 0; r < 4; ++r) {
                const int m = mrow + r;
                if (m < NFD) slab[(size_t)m * 128 + n] = acc[mf][nf][r];
            }
        }
    }
}

// ---------------------------------------------------------------------------
// reduce: fhat/ghat[b][f][k] = sum_ch partials[slab(ch,wh,b)][f*128 + k]
// ---------------------------------------------------------------------------
__global__ __launch_bounds__(256) void reduce_k(
    const float* __restrict__ partials, float* __restrict__ fhat, float* __restrict__ ghat)
{
    const int id = blockIdx.x * 256 + threadIdx.x;
    if (id >= NFD * KD) return;
    const int wb = blockIdx.y;
    const int wh = wb >> 4;
    const int b  = wb & 15;
    const int f = id / KD;
    const int k = id - f * KD;

    const size_t slabsz = 352 * 128;
    const float* p = partials + (size_t)(wh * NB + b) * slabsz + (size_t)f * 128 + k;
    const size_t chstride = (size_t)2 * NB * slabsz;

    float s = 0.f;
    #pragma unroll
    for (int c = 0; c < 4; ++c) s += p[c * chstride];

    float* dst = (wh ? ghat : fhat) + (size_t)b * NFD * KD + id;
    *dst = s;
}

// ---------------------------------------------------------------------------
// Generic TN SGEMM 64x64 tile — used by gram.
// ---------------------------------------------------------------------------
__device__ __forceinline__ void gemm_tn_64x64(
    const float* __restrict__ A, const float* __restrict__ B, float* __restrict__ C,
    int V, int M, int N, int m0, int n0)
{
    __shared__ float As[16][64];
    __shared__ float Bs[16][64];

    const int tid = threadIdx.x;
    const int tx = tid & 15;
    const int ty = tid >> 4;
    const int sr = tid >> 4;
    const int sc = (tid & 15) << 2;

    float acc[4][4] = {{0.f,0.f,0.f,0.f},{0.f,0.f,0.f,0.f},
                       {0.f,0.f,0.f,0.f},{0.f,0.f,0.f,0.f}};

    for (int v0 = 0; v0 < V; v0 += 16) {
        const int v = v0 + sr;
        float4 av; av.x = av.y = av.z = av.w = 0.f;
        float4 bv; bv.x = bv.y = bv.z = bv.w = 0.f;
        if (v < V) {
            const float* Ar = A + (size_t)v * M;
            const int ca = m0 + sc;
            if (ca + 3 < M) {
                av = *(const float4*)(Ar + ca);
            } else {
                if (ca + 0 < M) av.x = Ar[ca + 0];
                if (ca + 1 < M) av.y = Ar[ca + 1];
                if (ca + 2 < M) av.z = Ar[ca + 2];
                if (ca + 3 < M) av.w = Ar[ca + 3];
            }
            const float* Br = B + (size_t)v * N;
            const int cb = n0 + sc;
            if (cb + 3 < N) {
                bv = *(const float4*)(Br + cb);
            } else {
                if (cb + 0 < N) bv.x = Br[cb + 0];
                if (cb + 1 < N) bv.y = Br[cb + 1];
                if (cb + 2 < N) bv.z = Br[cb + 2];
                if (cb + 3 < N) bv.w = Br[cb + 3];
            }
        }
        __syncthreads();
        *(float4*)&As[sr][sc] = av;
        *(float4*)&Bs[sr][sc] = bv;
        __syncthreads();

        #pragma unroll
        for (int kk = 0; kk < 16; ++kk) {
            const float4 a4 = *(const float4*)&As[kk][ty << 2];
            const float4 b4 = *(const float4*)&Bs[kk][tx << 2];
            const float a[4]  = {a4.x, a4.y, a4.z, a4.w};
            const float bb[4] = {b4.x, b4.y, b4.z, b4.w};
            #pragma unroll
            for (int i = 0; i < 4; ++i)
                #pragma unroll
                for (int j = 0; j < 4; ++j)
                    acc[i][j] = fmaf(a[i], bb[j], acc[i][j]);
        }
    }

    #pragma unroll
    for (int i = 0; i < 4; ++i) {
        const int m = m0 + (ty << 2) + i;
        if (m < M) {
            #pragma unroll
            for (int j = 0; j < 4; ++j) {
                const int n = n0 + (tx << 2) + j;
                if (n < N) C[(size_t)m * N + n] = acc[i][j];
            }
        }
    }
}

__global__ __launch_bounds__(256) void gram_kernel(
    const float* __restrict__ fhat, const float* __restrict__ ghat,
    float* __restrict__ ftf, float* __restrict__ gtg, float* __restrict__ ftg)
{
    const int b = blockIdx.z;
    const int which = blockIdx.y;
    const int m0 = (blockIdx.x & 1) * 64;
    const int n0 = (blockIdx.x >> 1) * 64;

    const float* F = fhat + (size_t)b * NFD * KD;
    const float* G = ghat + (size_t)b * NFD * KD;
    const float* A  = (which == 1) ? G : F;
    const float* Bp = (which == 0) ? F : G;
    float* C = ((which == 0) ? ftf : (which == 1) ? gtg : ftg) + (size_t)b * KD * KD;

    gemm_tn_64x64(A, Bp, C, NFD, KD, KD, m0, n0);
}

// ---------------------------------------------------------------------------
// solve v4: Gauss-Jordan on [A|B] 120x240.
// Decomposition: 960 threads = one thread per (row, col-group).
//   row = tid >> 3   (0..119  — exactly the 120 live rows, no dead lanes)
//   cg  = tid & 7    (0..7),  cols cg*30 .. cg*30+29  (8*30 = 240 exactly)
// Each thread holds its 30 entries as NAMED SCALARS c0..c29 (no arrays ->
// nothing for the register allocator to demote to scratch; v1/v2 spilled,
// v3's float4-lane layout was wrong). Per step: read pivot row slice (30,
// LDS broadcast) + pivot col entry (1), rank-1 update, pivot-row fixup,
// publish next pivot row (8 threads x 30) / col (120 threads x 1, uniform
// switch), one barrier. Double-buffered prow/pcol.
// pair 0: X = inv(FtF)*FtG, out C1 = X^T; pair 1: X = inv(GtG)*FtG^T, C2 = X^T
// ---------------------------------------------------------------------------
__device__ __forceinline__ float ldval(const float* __restrict__ A, const float* __restrict__ B,
                                       int pair, int row, int col) {
    if (col < KD) return A[row * KD + col];
    const int l = col - KD;
    return pair ? B[l * KD + row] : B[row * KD + l];
}

#define FOR30(OP) OP(0) OP(1) OP(2) OP(3) OP(4) OP(5) OP(6) OP(7) OP(8) OP(9) \
                  OP(10) OP(11) OP(12) OP(13) OP(14) OP(15) OP(16) OP(17) OP(18) OP(19) \
                  OP(20) OP(21) OP(22) OP(23) OP(24) OP(25) OP(26) OP(27) OP(28) OP(29)

__global__ __launch_bounds__(960, 1) void solve_kernel(
    const float* __restrict__ ftf, const float* __restrict__ gtg,
    const float* __restrict__ ftg, float* __restrict__ out)
{
    const int pair = blockIdx.x;
    const int b = blockIdx.y;
    const int tid = threadIdx.x;
    const int row   = tid >> 3;   // 0..119
    const int cg    = tid & 7;    // 0..7
    const int cbase = cg * 30;    // first owned column

    const float* Ag = ((pair == 0) ? ftf : gtg) + (size_t)b * KD * KD;
    const float* Bg = ftg + (size_t)b * KD * KD;

    __shared__ float prow[2][240];
    __shared__ float pcol[2][120];

    // ---- load: 30 named scalars ----
    #define DECLC(I) float c##I = ldval(Ag, Bg, pair, row, cbase + (I));
    FOR30(DECLC)
    #undef DECLC

    // ---- publish pivot row 0 / pivot col 0 into buffer 0 ----
    if (row == 0) {
        #define PUBR0(I) prow[0][cbase + (I)] = c##I;
        FOR30(PUBR0)
        #undef PUBR0
    }
    if (cg == 0) pcol[0][row] = c0;   // column 0 is cg 0, scalar c0
    __syncthreads();

    for (int j = 0; j < KD; ++j) {
        const int cur = j & 1;
        const int nxt = cur ^ 1;

        const float pinv = 1.0f / prow[cur][j];

        // scaled pivot-row slice for this thread's 30 columns
        #define PRS(I) const float p##I = prow[cur][cbase + (I)] * pinv;
        FOR30(PRS)
        #undef PRS

        // this row's pivot-column entry (elimination factor)
        const float f = pcol[cur][row];

        // rank-1 update (pivot row itself zeroes out; fixed up below)
        #define UPDC(I) c##I = fmaf(-f, p##I, c##I);
        FOR30(UPDC)
        #undef UPDC

        // pivot row becomes the scaled pivot row
        if (row == j) {
            #define FIXC(I) c##I = p##I;
            FOR30(FIXC)
            #undef FIXC
        }

        // publish NEXT pivot row (j+1): 8 threads (row==j+1), 30 entries each
        const int j2 = j + 1;
        if (row == j2) {
            #define PUBR(I) prow[nxt][cbase + (I)] = c##I;
            FOR30(PUBR)
            #undef PUBR
        }
        // publish NEXT pivot column (j+1): 120 threads (cg owns it), 1 entry each.
        // j2 - cbase in [0,30) for the owning cg; uniform switch (block-uniform j2).
        if (j2 < KD && cg == (j2 / 30)) {
            #define PCASE(I) case I: pcol[nxt][row] = c##I; break;
            switch (j2 - cbase) {
                FOR30(PCASE)
                default: break;
            }
            #undef PCASE
        }
        __syncthreads();
    }

    // ---- write out X^T: out[pair][b][l][k] = X[k][l]; X = cols 120..239 (cg >= 4) ----
    float* op = out + (size_t)pair * NB * KD * KD + (size_t)b * KD * KD;
    if (cg >= 4) {
        #define OUTW(I) { const int l = cbase + (I) - KD; op[l * KD + row] = c##I; }
        FOR30(OUTW)
        #undef OUTW
    }
}

// ---------------------------------------------------------------------------
extern "C" void kernel_launch(void* const* d_in, const int* in_sizes, int n_in,
                              void* d_out, int out_size, void* d_ws, size_t ws_size,
                              hipStream_t stream)
{
    const float* feat_x  = (const float*)d_in[0];
    const float* feat_y  = (const float*)d_in[1];
    const float* evecs_x = (const float*)d_in[2];
    const float* evecs_y = (const float*)d_in[3];
    float* out = (float*)d_out;

    float* ws       = (float*)d_ws;
    float* zeropad  = ws;
    float* partials = ws + 64;
    float* fhat     = partials + (size_t)4 * 2 * NB * 352 * 128;
    float* ghat     = fhat + (size_t)NB * NFD * KD;
    float* ftf      = ghat + (size_t)NB * NFD * KD;
    float* gtg      = ftf  + (size_t)NB * KD * KD;
    float* ftg      = gtg  + (size_t)NB * KD * KD;

    hipMemsetAsync(zeropad, 0, 256, stream);

    proj_mfma <<<dim3(16, 2, NB), 256, 0, stream>>>(feat_x, feat_y, evecs_x, evecs_y, partials, zeropad);
    reduce_k  <<<dim3(165, 32), 256, 0, stream>>>(partials, fhat, ghat);
    gram_kernel<<<dim3(4, 3, NB), 256, 0, stream>>>(fhat, ghat, ftf, gtg, ftg);
    solve_kernel<<<dim3(2, NB), 960, 0, stream>>>(ftf, gtg, ftg, out);
}